// Round 1
// baseline (691.980 us; speedup 1.0000x reference)
//
#include <hip/hip_runtime.h>

#define N_NODES 100000
#define N_EDGES 1600000
#define F_IN    128
#define HID     256
#define C_OUT   4

#define NB_SCAN 391   // ceil(N_NODES/256)

// ---------------------------------------------------------------------------
// K1: in-degree count
__global__ void k_count_deg(const int* __restrict__ ei, int* __restrict__ deg) {
    int e = blockIdx.x * 256 + threadIdx.x;
    if (e < N_EDGES) atomicAdd(&deg[ei[N_EDGES + e]], 1);
}

// K2a: per-block inclusive scan of deg -> per-element exclusive + block sums
__global__ void k_scan_blocks(const int* __restrict__ deg, int* __restrict__ excl,
                              int* __restrict__ bsum) {
    __shared__ int sh[256];
    int t = threadIdx.x;
    int i = blockIdx.x * 256 + t;
    int v = (i < N_NODES) ? deg[i] : 0;
    sh[t] = v;
    __syncthreads();
    #pragma unroll
    for (int off = 1; off < 256; off <<= 1) {
        int add = (t >= off) ? sh[t - off] : 0;
        __syncthreads();
        sh[t] += add;
        __syncthreads();
    }
    if (i < N_NODES) excl[i] = sh[t] - v;
    if (t == 255) bsum[blockIdx.x] = sh[255];
}

// K2b: scan of block sums (single block, 512 threads >= NB_SCAN)
__global__ void k_scan_sums(const int* __restrict__ bsum, int* __restrict__ boff) {
    __shared__ int sh[512];
    int t = threadIdx.x;
    int v = (t < NB_SCAN) ? bsum[t] : 0;
    sh[t] = v;
    __syncthreads();
    #pragma unroll
    for (int off = 1; off < 512; off <<= 1) {
        int add = (t >= off) ? sh[t - off] : 0;
        __syncthreads();
        sh[t] += add;
        __syncthreads();
    }
    boff[t] = sh[t] - v;
}

// K2c: rowptr/cursor/inv_deg
__global__ void k_finalize(const int* __restrict__ deg, const int* __restrict__ excl,
                           const int* __restrict__ boff, int* __restrict__ rowptr,
                           int* __restrict__ cursor, float* __restrict__ inv_deg) {
    int i = blockIdx.x * 256 + threadIdx.x;
    if (i < N_NODES) {
        int r = excl[i] + boff[i >> 8];
        rowptr[i] = r;
        cursor[i] = r;
        int d = deg[i];
        inv_deg[i] = (d > 0) ? 1.0f / (float)d : 0.0f;
    }
    if (i == 0) rowptr[N_NODES] = N_EDGES;
}

// K3: scatter src indices into CSR slots
__global__ void k_fill_csr(const int* __restrict__ ei, int* __restrict__ cursor,
                           int* __restrict__ csr_src) {
    int e = blockIdx.x * 256 + threadIdx.x;
    if (e < N_EDGES) {
        int dst = ei[N_EDGES + e];
        int pos = atomicAdd(&cursor[dst], 1);
        csr_src[pos] = ei[e];
    }
}

// K4: mean-aggregate x over in-edges. One wave (64 lanes) per node; lane owns
// 2 of 128 feature dims -> each edge's row load is 64 lanes x 8B = 512B coalesced.
__global__ void k_aggregate(const float* __restrict__ x, const int* __restrict__ rowptr,
                            const int* __restrict__ csr_src, const float* __restrict__ inv_deg,
                            float* __restrict__ agg) {
    int lane = threadIdx.x & 63;
    int v = blockIdx.x * 4 + (threadIdx.x >> 6);
    if (v >= N_NODES) return;
    int r0 = rowptr[v], r1 = rowptr[v + 1];
    float ax = 0.f, ay = 0.f;
    for (int base = r0; base < r1; base += 64) {
        int idx = base + lane;
        int sv = (idx < r1) ? csr_src[idx] : 0;
        int cnt = min(64, r1 - base);
        for (int i = 0; i < cnt; ++i) {
            int s = __shfl(sv, i);
            float2 xv = *(const float2*)(x + (size_t)s * F_IN + 2 * lane);
            ax += xv.x;
            ay += xv.y;
        }
    }
    float id = inv_deg[v];
    float2 o = make_float2(ax * id, ay * id);
    *(float2*)(agg + (size_t)v * F_IN + 2 * lane) = o;
}

// K_prep: transpose w1_l, w1_r (HIDxF_IN row-major) to K-major [F_IN][HID]
__global__ void k_transpose_w(const float* __restrict__ w1l, const float* __restrict__ w1r,
                              float* __restrict__ wlT, float* __restrict__ wrT) {
    int i = blockIdx.x * 256 + threadIdx.x;
    if (i < HID * F_IN) {
        int j = i / F_IN, k = i % F_IN;
        wlT[k * HID + j] = w1l[i];
        wrT[k * HID + j] = w1r[i];
    }
}

// K5: fused  h = relu(agg @ w1_l.T + b1 + x @ w1_r.T);  z = h @ w2_l.T;  r = h @ w2_r.T
// h is never materialized to global. Block tile: 16 rows x 256 cols, 256 threads,
// 4x4 register tile per thread. Weights staged through LDS in K-chunks so each
// block reads them once (not once per wave).
#define TM 16
#define KB 16
__global__ __launch_bounds__(256) void k_fused(
    const float* __restrict__ agg, const float* __restrict__ x,
    const float* __restrict__ wlT, const float* __restrict__ wrT,
    const float* __restrict__ b1,
    const float* __restrict__ w2l, const float* __restrict__ w2r,
    float* __restrict__ zb, float* __restrict__ rb) {
    __shared__ float ash[TM][F_IN];   // 8 KB
    __shared__ float xsh[TM][F_IN];   // 8 KB
    __shared__ float wlsh[KB][HID];   // 16 KB
    __shared__ float wrsh[KB][HID];   // 16 KB

    int t = threadIdx.x;
    int row0 = blockIdx.x * TM;

    // stage the 16 agg rows + 16 x rows (4096 floats = 1024 float4)
    #pragma unroll
    for (int p = 0; p < 4; ++p) {
        int fi = t + p * 256;            // [0,1024)
        int arr = fi >> 9;               // 0: agg, 1: x
        int li = fi & 511;
        int m = li >> 5, c4 = (li & 31) * 4;
        const float* src = arr ? x : agg;
        float4 val = *(const float4*)(src + (size_t)(row0 + m) * F_IN + c4);
        float* dstp = arr ? &xsh[m][c4] : &ash[m][c4];
        *(float4*)dstp = val;
    }

    int tm4 = t >> 6;        // wave id = row group (4 rows)
    int tj = t & 63;         // col group (4 cols)
    int m0 = tm4 * 4;
    int j0 = tj * 4;

    float acc[4][4];
    #pragma unroll
    for (int a = 0; a < 4; ++a)
        #pragma unroll
        for (int b = 0; b < 4; ++b) acc[a][b] = 0.f;

    for (int kc = 0; kc < F_IN; kc += KB) {
        __syncthreads();
        // stage weight chunk: 2 * KB * HID floats = 2048 float4, 8 per thread
        #pragma unroll
        for (int p = 0; p < 8; ++p) {
            int f4 = t + p * 256;        // [0,2048)
            int which = f4 >> 10;
            int li = f4 & 1023;
            int kk = li >> 6, c4 = (li & 63) * 4;
            const float* src = which ? wrT : wlT;
            float4 val = *(const float4*)(src + (size_t)(kc + kk) * HID + c4);
            if (which) *(float4*)&wrsh[kk][c4] = val;
            else       *(float4*)&wlsh[kk][c4] = val;
        }
        __syncthreads();

        #pragma unroll
        for (int k4 = 0; k4 < KB; k4 += 4) {
            int k = kc + k4;
            float4 av[4], xv[4];
            #pragma unroll
            for (int mi = 0; mi < 4; ++mi) {
                av[mi] = *(const float4*)&ash[m0 + mi][k];   // wave-uniform: LDS broadcast
                xv[mi] = *(const float4*)&xsh[m0 + mi][k];
            }
            float4 wl[4], wr[4];
            #pragma unroll
            for (int kk = 0; kk < 4; ++kk) {
                wl[kk] = *(const float4*)&wlsh[k4 + kk][j0];
                wr[kk] = *(const float4*)&wrsh[k4 + kk][j0];
            }
            #pragma unroll
            for (int kk = 0; kk < 4; ++kk) {
                const float4 wlv = wl[kk], wrv = wr[kk];
                #pragma unroll
                for (int mi = 0; mi < 4; ++mi) {
                    const float a = (kk == 0) ? av[mi].x : (kk == 1) ? av[mi].y
                                   : (kk == 2) ? av[mi].z : av[mi].w;
                    const float xx = (kk == 0) ? xv[mi].x : (kk == 1) ? xv[mi].y
                                    : (kk == 2) ? xv[mi].z : xv[mi].w;
                    acc[mi][0] += a * wlv.x + xx * wrv.x;
                    acc[mi][1] += a * wlv.y + xx * wrv.y;
                    acc[mi][2] += a * wlv.z + xx * wrv.z;
                    acc[mi][3] += a * wlv.w + xx * wrv.w;
                }
            }
        }
    }

    // bias + relu -> h (still distributed: this thread holds h[m0+mi][j0..j0+3])
    float4 bv = *(const float4*)(b1 + j0);
    float h[4][4];
    #pragma unroll
    for (int mi = 0; mi < 4; ++mi) {
        h[mi][0] = fmaxf(acc[mi][0] + bv.x, 0.f);
        h[mi][1] = fmaxf(acc[mi][1] + bv.y, 0.f);
        h[mi][2] = fmaxf(acc[mi][2] + bv.z, 0.f);
        h[mi][3] = fmaxf(acc[mi][3] + bv.w, 0.f);
    }

    // layer-2 projections: partial dots over this thread's 4 cols, then
    // butterfly-reduce across the wave (each wave owns its 4 rows entirely).
    float pz[4][4], pr[4][4];
    #pragma unroll
    for (int c = 0; c < 4; ++c) {
        float4 wv = *(const float4*)(w2l + c * HID + j0);
        float4 wv2 = *(const float4*)(w2r + c * HID + j0);
        #pragma unroll
        for (int mi = 0; mi < 4; ++mi) {
            pz[mi][c] = h[mi][0] * wv.x + h[mi][1] * wv.y + h[mi][2] * wv.z + h[mi][3] * wv.w;
            pr[mi][c] = h[mi][0] * wv2.x + h[mi][1] * wv2.y + h[mi][2] * wv2.z + h[mi][3] * wv2.w;
        }
    }
    #pragma unroll
    for (int off = 1; off < 64; off <<= 1) {
        #pragma unroll
        for (int mi = 0; mi < 4; ++mi) {
            #pragma unroll
            for (int c = 0; c < 4; ++c) {
                pz[mi][c] += __shfl_xor(pz[mi][c], off);
                pr[mi][c] += __shfl_xor(pr[mi][c], off);
            }
        }
    }
    if (tj == 0) {
        #pragma unroll
        for (int mi = 0; mi < 4; ++mi) {
            int row = row0 + m0 + mi;
            *(float4*)(zb + (size_t)row * 4) = make_float4(pz[mi][0], pz[mi][1], pz[mi][2], pz[mi][3]);
            *(float4*)(rb + (size_t)row * 4) = make_float4(pr[mi][0], pr[mi][1], pr[mi][2], pr[mi][3]);
        }
    }
}

// K6: aggregate z over in-edges (one wave per node), add bias + root term,
// log_softmax over the 4 classes, write output.
__global__ void k_final(const float* __restrict__ zb, const float* __restrict__ rb,
                        const int* __restrict__ rowptr, const int* __restrict__ csr_src,
                        const float* __restrict__ inv_deg, const float* __restrict__ b2,
                        float* __restrict__ out) {
    int lane = threadIdx.x & 63;
    int v = blockIdx.x * 4 + (threadIdx.x >> 6);
    if (v >= N_NODES) return;
    int r0 = rowptr[v], r1 = rowptr[v + 1];
    float a0 = 0.f, a1 = 0.f, a2 = 0.f, a3 = 0.f;
    for (int idx = r0 + lane; idx < r1; idx += 64) {
        int s = csr_src[idx];
        float4 zv = *(const float4*)(zb + (size_t)s * 4);
        a0 += zv.x; a1 += zv.y; a2 += zv.z; a3 += zv.w;
    }
    #pragma unroll
    for (int off = 1; off < 64; off <<= 1) {
        a0 += __shfl_xor(a0, off);
        a1 += __shfl_xor(a1, off);
        a2 += __shfl_xor(a2, off);
        a3 += __shfl_xor(a3, off);
    }
    if (lane == 0) {
        float id = inv_deg[v];
        float4 rv = *(const float4*)(rb + (size_t)v * 4);
        float4 b2v = *(const float4*)b2;
        float h0 = a0 * id + b2v.x + rv.x;
        float h1 = a1 * id + b2v.y + rv.y;
        float h2 = a2 * id + b2v.z + rv.z;
        float h3 = a3 * id + b2v.w + rv.w;
        float mx = fmaxf(fmaxf(h0, h1), fmaxf(h2, h3));
        float s = expf(h0 - mx) + expf(h1 - mx) + expf(h2 - mx) + expf(h3 - mx);
        float lse = mx + logf(s);
        *(float4*)(out + (size_t)v * 4) = make_float4(h0 - lse, h1 - lse, h2 - lse, h3 - lse);
    }
}

// ---------------------------------------------------------------------------
extern "C" void kernel_launch(void* const* d_in, const int* in_sizes, int n_in,
                              void* d_out, int out_size, void* d_ws, size_t ws_size,
                              hipStream_t stream) {
    const float* x   = (const float*)d_in[0];
    const int*   ei  = (const int*)d_in[1];
    const float* w1l = (const float*)d_in[2];
    const float* w1r = (const float*)d_in[3];
    const float* b1  = (const float*)d_in[4];
    const float* w2l = (const float*)d_in[5];
    const float* w2r = (const float*)d_in[6];
    const float* b2  = (const float*)d_in[7];
    float* out = (float*)d_out;

    char* ws = (char*)d_ws;
    size_t off = 0;
    auto alloc = [&](size_t bytes) -> void* {
        void* p = ws + off;
        off = (off + bytes + 255) & ~(size_t)255;
        return p;
    };
    int* deg     = (int*)alloc(N_NODES * 4);
    int* excl    = (int*)alloc(N_NODES * 4);
    int* bsum    = (int*)alloc(512 * 4);
    int* boff    = (int*)alloc(512 * 4);
    int* rowptr  = (int*)alloc((N_NODES + 1) * 4);
    int* cursor  = (int*)alloc(N_NODES * 4);
    int* csr_src = (int*)alloc((size_t)N_EDGES * 4);
    float* inv_deg = (float*)alloc(N_NODES * 4);
    float* agg   = (float*)alloc((size_t)N_NODES * F_IN * 4);
    float* zb    = (float*)alloc((size_t)N_NODES * 4 * 4);
    float* rb    = (float*)alloc((size_t)N_NODES * 4 * 4);
    float* wlT   = (float*)alloc((size_t)F_IN * HID * 4);
    float* wrT   = (float*)alloc((size_t)F_IN * HID * 4);

    hipMemsetAsync(deg, 0, N_NODES * 4, stream);

    const int EB = (N_EDGES + 255) / 256;   // 6250
    k_count_deg<<<EB, 256, 0, stream>>>(ei, deg);
    k_scan_blocks<<<NB_SCAN, 256, 0, stream>>>(deg, excl, bsum);
    k_scan_sums<<<1, 512, 0, stream>>>(bsum, boff);
    k_finalize<<<NB_SCAN, 256, 0, stream>>>(deg, excl, boff, rowptr, cursor, inv_deg);
    k_fill_csr<<<EB, 256, 0, stream>>>(ei, cursor, csr_src);
    k_transpose_w<<<(HID * F_IN + 255) / 256, 256, 0, stream>>>(w1l, w1r, wlT, wrT);
    k_aggregate<<<(N_NODES + 3) / 4, 256, 0, stream>>>(x, rowptr, csr_src, inv_deg, agg);
    k_fused<<<N_NODES / TM, 256, 0, stream>>>(agg, x, wlT, wrT, b1, w2l, w2r, zb, rb);
    k_final<<<(N_NODES + 3) / 4, 256, 0, stream>>>(zb, rb, rowptr, csr_src, inv_deg, b2, out);
}

// Round 2
// 392.583 us; speedup vs baseline: 1.7626x; 1.7626x over previous
//
#include <hip/hip_runtime.h>

#define N_NODES 100000
#define N_ROWS_PAD 100032   // padded to multiple of 64 for the MFMA kernel
#define N_EDGES 1600000
#define F_IN    128
#define HID     256
#define C_OUT   4

#define NB_SCAN 391   // ceil(N_NODES/256)

typedef short short8v __attribute__((ext_vector_type(8)));
typedef float f32x4 __attribute__((ext_vector_type(4)));

__device__ __forceinline__ ushort f2b(float f) {
    union { float f; unsigned u; } v; v.f = f;
    unsigned u = v.u;
    return (ushort)((u + 0x7FFFu + ((u >> 16) & 1u)) >> 16);   // RNE
}
__device__ __forceinline__ float b2f(ushort u) {
    union { unsigned u; float f; } v; v.u = ((unsigned)u) << 16; return v.f;
}

// ---------------------------------------------------------------------------
// K1: in-degree count
__global__ void k_count_deg(const int* __restrict__ ei, int* __restrict__ deg) {
    int e = blockIdx.x * 256 + threadIdx.x;
    if (e < N_EDGES) atomicAdd(&deg[ei[N_EDGES + e]], 1);
}

// K2a: per-block inclusive scan of deg -> per-element exclusive + block sums
__global__ void k_scan_blocks(const int* __restrict__ deg, int* __restrict__ excl,
                              int* __restrict__ bsum) {
    __shared__ int sh[256];
    int t = threadIdx.x;
    int i = blockIdx.x * 256 + t;
    int v = (i < N_NODES) ? deg[i] : 0;
    sh[t] = v;
    __syncthreads();
    #pragma unroll
    for (int off = 1; off < 256; off <<= 1) {
        int add = (t >= off) ? sh[t - off] : 0;
        __syncthreads();
        sh[t] += add;
        __syncthreads();
    }
    if (i < N_NODES) excl[i] = sh[t] - v;
    if (t == 255) bsum[blockIdx.x] = sh[255];
}

// K2b: scan of block sums (single block, 512 threads >= NB_SCAN)
__global__ void k_scan_sums(const int* __restrict__ bsum, int* __restrict__ boff) {
    __shared__ int sh[512];
    int t = threadIdx.x;
    int v = (t < NB_SCAN) ? bsum[t] : 0;
    sh[t] = v;
    __syncthreads();
    #pragma unroll
    for (int off = 1; off < 512; off <<= 1) {
        int add = (t >= off) ? sh[t - off] : 0;
        __syncthreads();
        sh[t] += add;
        __syncthreads();
    }
    boff[t] = sh[t] - v;
}

// K2c: rowptr/cursor/inv_deg
__global__ void k_finalize(const int* __restrict__ deg, const int* __restrict__ excl,
                           const int* __restrict__ boff, int* __restrict__ rowptr,
                           int* __restrict__ cursor, float* __restrict__ inv_deg) {
    int i = blockIdx.x * 256 + threadIdx.x;
    if (i < N_NODES) {
        int r = excl[i] + boff[i >> 8];
        rowptr[i] = r;
        cursor[i] = r;
        int d = deg[i];
        inv_deg[i] = (d > 0) ? 1.0f / (float)d : 0.0f;
    }
    if (i == 0) rowptr[N_NODES] = N_EDGES;
}

// K3: scatter src indices into CSR slots
__global__ void k_fill_csr(const int* __restrict__ ei, int* __restrict__ cursor,
                           int* __restrict__ csr_src) {
    int e = blockIdx.x * 256 + threadIdx.x;
    if (e < N_EDGES) {
        int dst = ei[N_EDGES + e];
        int pos = atomicAdd(&cursor[dst], 1);
        csr_src[pos] = ei[e];
    }
}

// K_xcast: bf16-cast x into ABF[row][128:256]  (3.2M threads, each 4 floats)
__global__ void k_xcast(const float* __restrict__ x, ushort* __restrict__ abf) {
    int t = blockIdx.x * 256 + threadIdx.x;        // [0, 3.2M)
    float4 xv = *(const float4*)(x + (size_t)t * 4);
    int row = t >> 5;
    int colq = (t & 31) * 4;
    ushort4 o; o.x = f2b(xv.x); o.y = f2b(xv.y); o.z = f2b(xv.z); o.w = f2b(xv.w);
    *(ushort4*)(abf + (size_t)row * 256 + 128 + colq) = o;
}

// K_wbf: WBF[col][k] bf16, col 0..255, k 0..255: [w1_l | w1_r] along k
__global__ void k_wbf(const float* __restrict__ w1l, const float* __restrict__ w1r,
                      ushort* __restrict__ wbf) {
    int i = blockIdx.x * 256 + threadIdx.x;        // [0, 65536)
    int col = i >> 8, k = i & 255;
    float v = (k < 128) ? w1l[col * 128 + k] : w1r[col * 128 + (k - 128)];
    wbf[i] = f2b(v);
}

// K4: mean-aggregate bf16 x-rows over in-edges. One wave per node; half-wave
// per edge (32 lanes x 8B = 256B bf16 row), 2 edges per step.
__global__ void k_aggregate(const int* __restrict__ rowptr, const int* __restrict__ csr_src,
                            const float* __restrict__ inv_deg, ushort* __restrict__ abf) {
    int lane = threadIdx.x & 63;
    int v = blockIdx.x * 4 + (threadIdx.x >> 6);
    if (v >= N_NODES) return;
    int r0 = rowptr[v], r1 = rowptr[v + 1];
    int half = lane >> 5, li = lane & 31;
    float a0 = 0.f, a1 = 0.f, a2 = 0.f, a3 = 0.f;
    for (int base = r0; base < r1; base += 64) {
        int idx = base + lane;
        int sv = (idx < r1) ? csr_src[idx] : 0;
        int cnt = min(64, r1 - base);
        int steps = (cnt + 1) >> 1;
        for (int i = 0; i < steps; ++i) {
            int e = 2 * i + half;
            int s = __shfl(sv, e);
            if (e < cnt) {
                ushort4 uv = *(const ushort4*)(abf + (size_t)s * 256 + 128 + li * 4);
                a0 += b2f(uv.x); a1 += b2f(uv.y); a2 += b2f(uv.z); a3 += b2f(uv.w);
            }
        }
    }
    a0 += __shfl_xor(a0, 32);
    a1 += __shfl_xor(a1, 32);
    a2 += __shfl_xor(a2, 32);
    a3 += __shfl_xor(a3, 32);
    if (half == 0) {
        float id = inv_deg[v];
        ushort4 o;
        o.x = f2b(a0 * id); o.y = f2b(a1 * id); o.z = f2b(a2 * id); o.w = f2b(a3 * id);
        *(ushort4*)(abf + (size_t)v * 256 + li * 4) = o;
    }
}

// K5: MFMA GEMM  h = relu(ABF @ WBF^T + b1)  fused with layer-2 projections
//     z = h @ w2l^T, r = h @ w2r^T  (h never materialized).
// Block: 64 rows, 256 threads (4 waves). Wave w: rows row0+w*16..+15, all 256
// cols = 16 n-fragments, K=256 in 8 chunks of 32. B chunk (16KB) double-
// buffered in LDS, frag-ordered (lane-contiguous 16B -> conflict-free b128).
__global__ __launch_bounds__(256) void k_mfma(
    const ushort* __restrict__ abf, const ushort* __restrict__ wbf,
    const float* __restrict__ b1, const float* __restrict__ w2l,
    const float* __restrict__ w2r, float* __restrict__ zb, float* __restrict__ rb)
{
    __shared__ ushort shB[2][16 * 512];   // 2 x 16KB: [buf][frag n][lane*8]
    __shared__ float w2t[256][12];        // [col][c0..7 + pad] pad->48B stride
    __shared__ float b1sh[256];

    int t = threadIdx.x;
    int w = t >> 6, l = t & 63;
    int lr = l & 15, lk = l >> 4;
    int row0 = blockIdx.x * 64;

    b1sh[t] = b1[t];
    #pragma unroll
    for (int c = 0; c < 4; ++c) {
        w2t[t][c]     = w2l[c * HID + t];
        w2t[t][c + 4] = w2r[c * HID + t];
    }

    // A fragments for all 8 K-chunks, hoisted (sequential 64B walk per row)
    const ushort* ap = abf + (size_t)(row0 + w * 16 + lr) * 256 + lk * 8;
    short8v afr[8];
    #pragma unroll
    for (int ks = 0; ks < 8; ++ks)
        afr[ks] = *(const short8v*)(ap + ks * 32);

    // stage B chunk 0 (wave w owns frags n = w*4..w*4+3)
    short8v breg[4];
    #pragma unroll
    for (int ni = 0; ni < 4; ++ni) {
        int n = w * 4 + ni;
        breg[ni] = *(const short8v*)(wbf + (size_t)(n * 16 + lr) * 256 + lk * 8);
    }
    #pragma unroll
    for (int ni = 0; ni < 4; ++ni)
        *(short8v*)&shB[0][(w * 4 + ni) * 512 + l * 8] = breg[ni];
    __syncthreads();

    f32x4 acc[16] = {};
    #pragma unroll
    for (int ks = 0; ks < 8; ++ks) {
        int cur = ks & 1;
        if (ks < 7) {   // issue next chunk's global loads early (latency hide)
            #pragma unroll
            for (int ni = 0; ni < 4; ++ni) {
                int n = w * 4 + ni;
                breg[ni] = *(const short8v*)(wbf + (size_t)(n * 16 + lr) * 256 + (ks + 1) * 32 + lk * 8);
            }
        }
        #pragma unroll
        for (int n = 0; n < 16; ++n) {
            short8v bf = *(const short8v*)&shB[cur][n * 512 + l * 8];
            acc[n] = __builtin_amdgcn_mfma_f32_16x16x32_bf16(afr[ks], bf, acc[n], 0, 0, 0);
        }
        if (ks < 7) {
            #pragma unroll
            for (int ni = 0; ni < 4; ++ni)
                *(short8v*)&shB[cur ^ 1][(w * 4 + ni) * 512 + l * 8] = breg[ni];
        }
        __syncthreads();
    }

    // epilogue: bias+relu, layer-2 partial dots over this lane's 16 cols,
    // butterfly-reduce over the 16 lanes sharing a row group.
    float pz[4][8];
    #pragma unroll
    for (int q = 0; q < 4; ++q)
        #pragma unroll
        for (int c = 0; c < 8; ++c) pz[q][c] = 0.f;

    #pragma unroll
    for (int n = 0; n < 16; ++n) {
        int col = n * 16 + lr;
        float bias = b1sh[col];
        f32x4 wa = *(const f32x4*)&w2t[col][0];
        f32x4 wb = *(const f32x4*)&w2t[col][4];
        #pragma unroll
        for (int q = 0; q < 4; ++q) {
            float h = fmaxf(acc[n][q] + bias, 0.f);
            pz[q][0] += h * wa[0]; pz[q][1] += h * wa[1];
            pz[q][2] += h * wa[2]; pz[q][3] += h * wa[3];
            pz[q][4] += h * wb[0]; pz[q][5] += h * wb[1];
            pz[q][6] += h * wb[2]; pz[q][7] += h * wb[3];
        }
    }
    #pragma unroll
    for (int off = 1; off < 16; off <<= 1)
        #pragma unroll
        for (int q = 0; q < 4; ++q)
            #pragma unroll
            for (int c = 0; c < 8; ++c)
                pz[q][c] += __shfl_xor(pz[q][c], off);

    if (lr == 0) {
        #pragma unroll
        for (int q = 0; q < 4; ++q) {
            int row = row0 + w * 16 + lk * 4 + q;   // C/D: row=(lane>>4)*4+reg
            if (row < N_NODES) {
                *(float4*)(zb + (size_t)row * 4) = make_float4(pz[q][0], pz[q][1], pz[q][2], pz[q][3]);
                *(float4*)(rb + (size_t)row * 4) = make_float4(pz[q][4], pz[q][5], pz[q][6], pz[q][7]);
            }
        }
    }
}

// K6: aggregate z over in-edges (one wave per node), add bias + root term,
// log_softmax over the 4 classes, write output.
__global__ void k_final(const float* __restrict__ zb, const float* __restrict__ rb,
                        const int* __restrict__ rowptr, const int* __restrict__ csr_src,
                        const float* __restrict__ inv_deg, const float* __restrict__ b2,
                        float* __restrict__ out) {
    int lane = threadIdx.x & 63;
    int v = blockIdx.x * 4 + (threadIdx.x >> 6);
    if (v >= N_NODES) return;
    int r0 = rowptr[v], r1 = rowptr[v + 1];
    float a0 = 0.f, a1 = 0.f, a2 = 0.f, a3 = 0.f;
    for (int idx = r0 + lane; idx < r1; idx += 64) {
        int s = csr_src[idx];
        float4 zv = *(const float4*)(zb + (size_t)s * 4);
        a0 += zv.x; a1 += zv.y; a2 += zv.z; a3 += zv.w;
    }
    #pragma unroll
    for (int off = 1; off < 64; off <<= 1) {
        a0 += __shfl_xor(a0, off);
        a1 += __shfl_xor(a1, off);
        a2 += __shfl_xor(a2, off);
        a3 += __shfl_xor(a3, off);
    }
    if (lane == 0) {
        float id = inv_deg[v];
        float4 rv = *(const float4*)(rb + (size_t)v * 4);
        float4 b2v = *(const float4*)b2;
        float h0 = a0 * id + b2v.x + rv.x;
        float h1 = a1 * id + b2v.y + rv.y;
        float h2 = a2 * id + b2v.z + rv.z;
        float h3 = a3 * id + b2v.w + rv.w;
        float mx = fmaxf(fmaxf(h0, h1), fmaxf(h2, h3));
        float s = expf(h0 - mx) + expf(h1 - mx) + expf(h2 - mx) + expf(h3 - mx);
        float lse = mx + logf(s);
        *(float4*)(out + (size_t)v * 4) = make_float4(h0 - lse, h1 - lse, h2 - lse, h3 - lse);
    }
}

// ---------------------------------------------------------------------------
extern "C" void kernel_launch(void* const* d_in, const int* in_sizes, int n_in,
                              void* d_out, int out_size, void* d_ws, size_t ws_size,
                              hipStream_t stream) {
    const float* x   = (const float*)d_in[0];
    const int*   ei  = (const int*)d_in[1];
    const float* w1l = (const float*)d_in[2];
    const float* w1r = (const float*)d_in[3];
    const float* b1  = (const float*)d_in[4];
    const float* w2l = (const float*)d_in[5];
    const float* w2r = (const float*)d_in[6];
    const float* b2  = (const float*)d_in[7];
    float* out = (float*)d_out;

    char* ws = (char*)d_ws;
    size_t off = 0;
    auto alloc = [&](size_t bytes) -> void* {
        void* p = ws + off;
        off = (off + bytes + 255) & ~(size_t)255;
        return p;
    };
    int* deg     = (int*)alloc(N_NODES * 4);
    int* excl    = (int*)alloc(N_NODES * 4);
    int* bsum    = (int*)alloc(512 * 4);
    int* boff    = (int*)alloc(512 * 4);
    int* rowptr  = (int*)alloc((N_NODES + 1) * 4);
    int* cursor  = (int*)alloc(N_NODES * 4);
    int* csr_src = (int*)alloc((size_t)N_EDGES * 4);
    float* inv_deg = (float*)alloc(N_NODES * 4);
    ushort* abf  = (ushort*)alloc((size_t)N_ROWS_PAD * 256 * 2);  // [agg | x] bf16
    ushort* wbf  = (ushort*)alloc((size_t)256 * 256 * 2);         // [w1l | w1r] bf16, [col][k]
    float* zb    = (float*)alloc((size_t)N_NODES * 4 * 4);
    float* rb    = (float*)alloc((size_t)N_NODES * 4 * 4);

    hipMemsetAsync(deg, 0, N_NODES * 4, stream);

    const int EB = (N_EDGES + 255) / 256;   // 6250
    k_count_deg<<<EB, 256, 0, stream>>>(ei, deg);
    k_scan_blocks<<<NB_SCAN, 256, 0, stream>>>(deg, excl, bsum);
    k_scan_sums<<<1, 512, 0, stream>>>(bsum, boff);
    k_finalize<<<NB_SCAN, 256, 0, stream>>>(deg, excl, boff, rowptr, cursor, inv_deg);
    k_fill_csr<<<EB, 256, 0, stream>>>(ei, cursor, csr_src);
    k_wbf<<<256, 256, 0, stream>>>(w1l, w1r, wbf);
    k_xcast<<<12500, 256, 0, stream>>>(x, abf);
    k_aggregate<<<(N_NODES + 3) / 4, 256, 0, stream>>>(rowptr, csr_src, inv_deg, abf);
    k_mfma<<<N_ROWS_PAD / 64, 256, 0, stream>>>(abf, wbf, b1, w2l, w2r, zb, rb);
    k_final<<<(N_NODES + 3) / 4, 256, 0, stream>>>(zb, rb, rowptr, csr_src, inv_deg, b2, out);
}

// Round 3
// 290.958 us; speedup vs baseline: 2.3783x; 1.3493x over previous
//
#include <hip/hip_runtime.h>

#define N_NODES 100000
#define N_ROWS_PAD 100032   // padded to multiple of 64 for the MFMA kernel
#define N_EDGES 1600000
#define F_IN    128
#define HID     256
#define C_OUT   4

#define NB 391        // ceil(N_NODES/256) buckets / scan blocks
#define EPT 16        // edges per thread in k_bucket

typedef short short8v __attribute__((ext_vector_type(8)));
typedef unsigned short u16x8 __attribute__((ext_vector_type(8)));
typedef float f32x4 __attribute__((ext_vector_type(4)));

__device__ __forceinline__ ushort f2b(float f) {
    union { float f; unsigned u; } v; v.f = f;
    unsigned u = v.u;
    return (ushort)((u + 0x7FFFu + ((u >> 16) & 1u)) >> 16);   // RNE
}
__device__ __forceinline__ float b2f(ushort u) {
    union { unsigned u; float f; } v; v.u = ((unsigned)u) << 16; return v.f;
}

// ---------------------------------------------------------------------------
// K1: in-degree count
__global__ void k_count_deg(const int* __restrict__ ei, int* __restrict__ deg) {
    int e = blockIdx.x * 256 + threadIdx.x;
    if (e < N_EDGES) atomicAdd(&deg[ei[N_EDGES + e]], 1);
}

// K2a: per-block inclusive scan of deg -> per-element exclusive + block sums
__global__ void k_scan_blocks(const int* __restrict__ deg, int* __restrict__ excl,
                              int* __restrict__ bsum) {
    __shared__ int sh[256];
    int t = threadIdx.x;
    int i = blockIdx.x * 256 + t;
    int v = (i < N_NODES) ? deg[i] : 0;
    sh[t] = v;
    __syncthreads();
    #pragma unroll
    for (int off = 1; off < 256; off <<= 1) {
        int add = (t >= off) ? sh[t - off] : 0;
        __syncthreads();
        sh[t] += add;
        __syncthreads();
    }
    if (i < N_NODES) excl[i] = sh[t] - v;
    if (t == 255) bsum[blockIdx.x] = sh[255];
}

// K2b: scan of block sums (single block, 512 threads >= NB)
__global__ void k_scan_sums(const int* __restrict__ bsum, int* __restrict__ boff) {
    __shared__ int sh[512];
    int t = threadIdx.x;
    int v = (t < NB) ? bsum[t] : 0;
    sh[t] = v;
    __syncthreads();
    #pragma unroll
    for (int off = 1; off < 512; off <<= 1) {
        int add = (t >= off) ? sh[t - off] : 0;
        __syncthreads();
        sh[t] += add;
        __syncthreads();
    }
    boff[t] = sh[t] - v;
}

// K2c: rowptr / inv_deg / bucket cursors
__global__ void k_finalize(const int* __restrict__ deg, const int* __restrict__ excl,
                           const int* __restrict__ boff, int* __restrict__ rowptr,
                           int* __restrict__ bcur, float* __restrict__ inv_deg) {
    int i = blockIdx.x * 256 + threadIdx.x;
    if (i < N_NODES) {
        int r = excl[i] + boff[i >> 8];
        rowptr[i] = r;
        int d = deg[i];
        inv_deg[i] = (d > 0) ? 1.0f / (float)d : 0.0f;
    }
    if (i < 512) bcur[i] = boff[i];
    if (i == 0) rowptr[N_NODES] = N_EDGES;
}

// K3a: bucket edges by dst>>8. Block-local LDS histogram -> one global atomic
// per (block,bucket) reserves a contiguous run -> clustered int2 writes.
__global__ __launch_bounds__(256) void k_bucket(const int* __restrict__ ei,
                                                int* __restrict__ bcur,
                                                int2* __restrict__ ebuf) {
    __shared__ int hist[NB];
    __shared__ int sbase[NB];
    int t = threadIdx.x;
    for (int i = t; i < NB; i += 256) hist[i] = 0;
    __syncthreads();
    int src[EPT], dst[EPT], lofs[EPT];
    int base = blockIdx.x * (256 * EPT);
    #pragma unroll
    for (int i = 0; i < EPT; ++i) {
        int e = base + i * 256 + t;
        if (e < N_EDGES) {
            src[i] = ei[e];
            dst[i] = ei[N_EDGES + e];
            lofs[i] = atomicAdd(&hist[dst[i] >> 8], 1);
        } else dst[i] = -1;
    }
    __syncthreads();
    for (int i = t; i < NB; i += 256) {
        int h = hist[i];
        sbase[i] = h ? atomicAdd(&bcur[i], h) : 0;
    }
    __syncthreads();
    #pragma unroll
    for (int i = 0; i < EPT; ++i) {
        if (dst[i] >= 0)
            ebuf[sbase[dst[i] >> 8] + lofs[i]] = make_int2(src[i], dst[i]);
    }
}

// K3b: one block per bucket; LDS cursors; csr_src writes confined to this
// bucket's contiguous ~16KB CSR window -> full-line fills, no XCD sharing.
__global__ __launch_bounds__(256) void k_place(const int* __restrict__ boff,
                                               const int2* __restrict__ ebuf,
                                               const int* __restrict__ rowptr,
                                               int* __restrict__ csr_src) {
    __shared__ int lcur[256];
    int b = blockIdx.x, t = threadIdx.x;
    int node0 = b * 256;
    if (node0 + t < N_NODES) lcur[t] = rowptr[node0 + t];
    __syncthreads();
    int e1 = boff[b + 1];
    for (int i = boff[b] + t; i < e1; i += 256) {
        int2 ed = ebuf[i];
        int pos = atomicAdd(&lcur[ed.y & 255], 1);
        csr_src[pos] = ed.x;
    }
}

// K_xcast: bf16-cast x into ABF[row][128:256]  (3.2M threads, each 4 floats)
__global__ void k_xcast(const float* __restrict__ x, ushort* __restrict__ abf) {
    int t = blockIdx.x * 256 + threadIdx.x;        // [0, 3.2M)
    float4 xv = *(const float4*)(x + (size_t)t * 4);
    int row = t >> 5;
    int colq = (t & 31) * 4;
    ushort4 o; o.x = f2b(xv.x); o.y = f2b(xv.y); o.z = f2b(xv.z); o.w = f2b(xv.w);
    *(ushort4*)(abf + (size_t)row * 256 + 128 + colq) = o;
}

// K_wbf: WBF[col][k] bf16, col 0..255, k 0..255: [w1_l | w1_r] along k
__global__ void k_wbf(const float* __restrict__ w1l, const float* __restrict__ w1r,
                      ushort* __restrict__ wbf) {
    int i = blockIdx.x * 256 + threadIdx.x;        // [0, 65536)
    int col = i >> 8, k = i & 255;
    float v = (k < 128) ? w1l[col * 128 + k] : w1r[col * 128 + (k - 128)];
    wbf[i] = f2b(v);
}

// K4: mean-aggregate bf16 x-rows over in-edges. One wave per node; 16 lanes
// per edge (16 x 16B = 256B row), 4 edges in flight per step.
__global__ void k_aggregate(const int* __restrict__ rowptr, const int* __restrict__ csr_src,
                            const float* __restrict__ inv_deg, ushort* __restrict__ abf) {
    int lane = threadIdx.x & 63;
    int v = blockIdx.x * 4 + (threadIdx.x >> 6);
    if (v >= N_NODES) return;
    int r0 = rowptr[v], r1 = rowptr[v + 1];
    int q = lane >> 4, li = lane & 15;
    float acc[8];
    #pragma unroll
    for (int j = 0; j < 8; ++j) acc[j] = 0.f;
    for (int bse = r0; bse < r1; bse += 64) {
        int idx = bse + lane;
        int sv = (idx < r1) ? csr_src[idx] : 0;
        int cnt = min(64, r1 - bse);
        int steps = (cnt + 3) >> 2;
        for (int i = 0; i < steps; ++i) {
            int e = 4 * i + q;
            int s = __shfl(sv, e);
            if (e < cnt) {
                u16x8 uv = *(const u16x8*)(abf + (size_t)s * 256 + 128 + li * 8);
                #pragma unroll
                for (int j = 0; j < 8; ++j) acc[j] += b2f(uv[j]);
            }
        }
    }
    #pragma unroll
    for (int j = 0; j < 8; ++j) {
        acc[j] += __shfl_xor(acc[j], 16);
        acc[j] += __shfl_xor(acc[j], 32);
    }
    if (q == 0) {
        float id = inv_deg[v];
        u16x8 o;
        #pragma unroll
        for (int j = 0; j < 8; ++j) o[j] = f2b(acc[j] * id);
        *(u16x8*)(abf + (size_t)v * 256 + li * 8) = o;
    }
}

// K5: MFMA GEMM  h = relu(ABF @ WBF^T + b1)  fused with layer-2 projections
//     z = h @ w2l^T, r = h @ w2r^T  (h never materialized).
__global__ __launch_bounds__(256) void k_mfma(
    const ushort* __restrict__ abf, const ushort* __restrict__ wbf,
    const float* __restrict__ b1, const float* __restrict__ w2l,
    const float* __restrict__ w2r, float* __restrict__ zb, float* __restrict__ rb)
{
    __shared__ ushort shB[2][16 * 512];   // 2 x 16KB: [buf][frag n][lane*8]
    __shared__ float w2t[256][12];        // [col][c0..7 + pad] pad->48B stride
    __shared__ float b1sh[256];

    int t = threadIdx.x;
    int w = t >> 6, l = t & 63;
    int lr = l & 15, lk = l >> 4;
    int row0 = blockIdx.x * 64;

    b1sh[t] = b1[t];
    #pragma unroll
    for (int c = 0; c < 4; ++c) {
        w2t[t][c]     = w2l[c * HID + t];
        w2t[t][c + 4] = w2r[c * HID + t];
    }

    // A fragments for all 8 K-chunks, hoisted
    const ushort* ap = abf + (size_t)(row0 + w * 16 + lr) * 256 + lk * 8;
    short8v afr[8];
    #pragma unroll
    for (int ks = 0; ks < 8; ++ks)
        afr[ks] = *(const short8v*)(ap + ks * 32);

    // stage B chunk 0 (wave w owns frags n = w*4..w*4+3)
    short8v breg[4];
    #pragma unroll
    for (int ni = 0; ni < 4; ++ni) {
        int n = w * 4 + ni;
        breg[ni] = *(const short8v*)(wbf + (size_t)(n * 16 + lr) * 256 + lk * 8);
    }
    #pragma unroll
    for (int ni = 0; ni < 4; ++ni)
        *(short8v*)&shB[0][(w * 4 + ni) * 512 + l * 8] = breg[ni];
    __syncthreads();

    f32x4 acc[16] = {};
    #pragma unroll
    for (int ks = 0; ks < 8; ++ks) {
        int cur = ks & 1;
        if (ks < 7) {   // issue next chunk's global loads early
            #pragma unroll
            for (int ni = 0; ni < 4; ++ni) {
                int n = w * 4 + ni;
                breg[ni] = *(const short8v*)(wbf + (size_t)(n * 16 + lr) * 256 + (ks + 1) * 32 + lk * 8);
            }
        }
        #pragma unroll
        for (int n = 0; n < 16; ++n) {
            short8v bf = *(const short8v*)&shB[cur][n * 512 + l * 8];
            acc[n] = __builtin_amdgcn_mfma_f32_16x16x32_bf16(afr[ks], bf, acc[n], 0, 0, 0);
        }
        if (ks < 7) {
            #pragma unroll
            for (int ni = 0; ni < 4; ++ni)
                *(short8v*)&shB[cur ^ 1][(w * 4 + ni) * 512 + l * 8] = breg[ni];
        }
        __syncthreads();
    }

    // epilogue: bias+relu, layer-2 partial dots, 16-lane butterfly reduce
    float pz[4][8];
    #pragma unroll
    for (int q = 0; q < 4; ++q)
        #pragma unroll
        for (int c = 0; c < 8; ++c) pz[q][c] = 0.f;

    #pragma unroll
    for (int n = 0; n < 16; ++n) {
        int col = n * 16 + lr;
        float bias = b1sh[col];
        f32x4 wa = *(const f32x4*)&w2t[col][0];
        f32x4 wb = *(const f32x4*)&w2t[col][4];
        #pragma unroll
        for (int q = 0; q < 4; ++q) {
            float h = fmaxf(acc[n][q] + bias, 0.f);
            pz[q][0] += h * wa[0]; pz[q][1] += h * wa[1];
            pz[q][2] += h * wa[2]; pz[q][3] += h * wa[3];
            pz[q][4] += h * wb[0]; pz[q][5] += h * wb[1];
            pz[q][6] += h * wb[2]; pz[q][7] += h * wb[3];
        }
    }
    #pragma unroll
    for (int off = 1; off < 16; off <<= 1)
        #pragma unroll
        for (int q = 0; q < 4; ++q)
            #pragma unroll
            for (int c = 0; c < 8; ++c)
                pz[q][c] += __shfl_xor(pz[q][c], off);

    if (lr == 0) {
        #pragma unroll
        for (int q = 0; q < 4; ++q) {
            int row = row0 + w * 16 + lk * 4 + q;   // C/D: row=(lane>>4)*4+reg
            if (row < N_NODES) {
                *(float4*)(zb + (size_t)row * 4) = make_float4(pz[q][0], pz[q][1], pz[q][2], pz[q][3]);
                *(float4*)(rb + (size_t)row * 4) = make_float4(pz[q][4], pz[q][5], pz[q][6], pz[q][7]);
            }
        }
    }
}

// K6: aggregate z over in-edges, add bias + root term, log_softmax, write out.
__global__ void k_final(const float* __restrict__ zb, const float* __restrict__ rb,
                        const int* __restrict__ rowptr, const int* __restrict__ csr_src,
                        const float* __restrict__ inv_deg, const float* __restrict__ b2,
                        float* __restrict__ out) {
    int lane = threadIdx.x & 63;
    int v = blockIdx.x * 4 + (threadIdx.x >> 6);
    if (v >= N_NODES) return;
    int r0 = rowptr[v], r1 = rowptr[v + 1];
    float a0 = 0.f, a1 = 0.f, a2 = 0.f, a3 = 0.f;
    for (int idx = r0 + lane; idx < r1; idx += 64) {
        int s = csr_src[idx];
        float4 zv = *(const float4*)(zb + (size_t)s * 4);
        a0 += zv.x; a1 += zv.y; a2 += zv.z; a3 += zv.w;
    }
    #pragma unroll
    for (int off = 1; off < 64; off <<= 1) {
        a0 += __shfl_xor(a0, off);
        a1 += __shfl_xor(a1, off);
        a2 += __shfl_xor(a2, off);
        a3 += __shfl_xor(a3, off);
    }
    if (lane == 0) {
        float id = inv_deg[v];
        float4 rv = *(const float4*)(rb + (size_t)v * 4);
        float4 b2v = *(const float4*)b2;
        float h0 = a0 * id + b2v.x + rv.x;
        float h1 = a1 * id + b2v.y + rv.y;
        float h2 = a2 * id + b2v.z + rv.z;
        float h3 = a3 * id + b2v.w + rv.w;
        float mx = fmaxf(fmaxf(h0, h1), fmaxf(h2, h3));
        float s = expf(h0 - mx) + expf(h1 - mx) + expf(h2 - mx) + expf(h3 - mx);
        float lse = mx + logf(s);
        *(float4*)(out + (size_t)v * 4) = make_float4(h0 - lse, h1 - lse, h2 - lse, h3 - lse);
    }
}

// ---------------------------------------------------------------------------
extern "C" void kernel_launch(void* const* d_in, const int* in_sizes, int n_in,
                              void* d_out, int out_size, void* d_ws, size_t ws_size,
                              hipStream_t stream) {
    const float* x   = (const float*)d_in[0];
    const int*   ei  = (const int*)d_in[1];
    const float* w1l = (const float*)d_in[2];
    const float* w1r = (const float*)d_in[3];
    const float* b1  = (const float*)d_in[4];
    const float* w2l = (const float*)d_in[5];
    const float* w2r = (const float*)d_in[6];
    const float* b2  = (const float*)d_in[7];
    float* out = (float*)d_out;

    char* ws = (char*)d_ws;
    size_t off = 0;
    auto alloc = [&](size_t bytes) -> void* {
        void* p = ws + off;
        off = (off + bytes + 255) & ~(size_t)255;
        return p;
    };
    int* deg     = (int*)alloc(N_NODES * 4);
    int* excl    = (int*)alloc(N_NODES * 4);
    int* bsum    = (int*)alloc(512 * 4);
    int* boff    = (int*)alloc(512 * 4);
    int* rowptr  = (int*)alloc((N_NODES + 1) * 4);
    int* bcur    = (int*)alloc(512 * 4);
    int* csr_src = (int*)alloc((size_t)N_EDGES * 4);
    int2* ebuf   = (int2*)alloc((size_t)N_EDGES * 8);
    float* inv_deg = (float*)alloc(N_NODES * 4);
    ushort* abf  = (ushort*)alloc((size_t)N_ROWS_PAD * 256 * 2);  // [agg | x] bf16
    ushort* wbf  = (ushort*)alloc((size_t)256 * 256 * 2);         // [w1l | w1r] bf16
    float* zb    = (float*)alloc((size_t)N_NODES * 4 * 4);
    float* rb    = (float*)alloc((size_t)N_NODES * 4 * 4);

    hipMemsetAsync(deg, 0, N_NODES * 4, stream);

    const int EB = (N_EDGES + 255) / 256;   // 6250
    k_count_deg<<<EB, 256, 0, stream>>>(ei, deg);
    k_scan_blocks<<<NB, 256, 0, stream>>>(deg, excl, bsum);
    k_scan_sums<<<1, 512, 0, stream>>>(bsum, boff);
    k_finalize<<<NB, 256, 0, stream>>>(deg, excl, boff, rowptr, bcur, inv_deg);
    k_bucket<<<(N_EDGES + 256 * EPT - 1) / (256 * EPT), 256, 0, stream>>>(ei, bcur, ebuf);
    k_place<<<NB, 256, 0, stream>>>(boff, ebuf, rowptr, csr_src);
    k_wbf<<<256, 256, 0, stream>>>(w1l, w1r, wbf);
    k_xcast<<<12500, 256, 0, stream>>>(x, abf);
    k_aggregate<<<(N_NODES + 3) / 4, 256, 0, stream>>>(rowptr, csr_src, inv_deg, abf);
    k_mfma<<<N_ROWS_PAD / 64, 256, 0, stream>>>(abf, wbf, b1, w2l, w2r, zb, rb);
    k_final<<<(N_NODES + 3) / 4, 256, 0, stream>>>(zb, rb, rowptr, csr_src, inv_deg, b2, out);
}